// Round 10
// baseline (1470.353 us; speedup 1.0000x reference)
//
#include <hip/hip_runtime.h>

// Problem constants: B=32, TX=TY=64, D=H=512, 4H=2048, V=32000.
typedef unsigned short ushort_t;
typedef _Float16 half_t;
typedef __attribute__((ext_vector_type(8))) short short8;     // 8 bf16 = 4 VGPRs
typedef __attribute__((ext_vector_type(8))) _Float16 half8;   // 8 fp16 = 4 VGPRs
typedef __attribute__((ext_vector_type(4))) _Float16 half4;
typedef __attribute__((ext_vector_type(4))) float f32x4;      // MFMA 16x16 acc

__device__ __forceinline__ ushort_t f2bf(float x) {
  union { float f; unsigned int u; } v; v.f = x;
  unsigned int r = v.u + 0x7fffu + ((v.u >> 16) & 1u);  // RNE
  return (ushort_t)(r >> 16);
}
__device__ __forceinline__ float bf2f(ushort_t h) {
  union { unsigned int u; float f; } v; v.u = ((unsigned int)h) << 16; return v.f;
}
__device__ __forceinline__ void splitbf(float x, ushort_t& hi, ushort_t& lo) {
  hi = f2bf(x);
  lo = f2bf(x - bf2f(hi));
}
__device__ __forceinline__ float sigm(float x) { return 1.f / (1.f + expf(-x)); }
__device__ __forceinline__ f32x4 mfma16(short8 a, short8 b, f32x4 c) {
  return __builtin_amdgcn_mfma_f32_16x16x32_bf16(a, b, c, 0, 0, 0);
}
__device__ __forceinline__ f32x4 mfma16h(half8 a, half8 b, f32x4 c) {
  return __builtin_amdgcn_mfma_f32_16x16x32_f16(a, b, c, 0, 0, 0);
}

// Async global->LDS, 16B per lane. LDS dest is wave-uniform base + lane*16
// (hardware rule, m104); global src is per-lane.
__device__ __forceinline__ void gload16(const void* g, void* l) {
  __builtin_amdgcn_global_load_lds(
      (const __attribute__((address_space(1))) unsigned int*)g,
      (__attribute__((address_space(3))) unsigned int*)l, 16, 0, 0);
}

// Counting barrier over the 32-block bm-group. cnt slot (bar*2+bm)*32 is a
// zero-initialized (zero_ints kernel) per-(step,group) counter in its own
// 128B line. Release semantics IDENTICAL to the R1-verified flag barrier:
// per-wave vmcnt(0) drains the write-through h stores to the coherence point,
// __syncthreads joins all waves, then ONE relaxed-agent VMEM op publishes.
// Only the poll topology changed: one fetch_add + single-line poll by lane 0
// instead of 32 lanes spinning on 32 distinct lines (poll-storm removal).
// Monotone within launch; counters re-zeroed every launch. Deadlock-free:
// every block increments exactly once per bar, then waits for ==32.
__device__ __forceinline__ void gridbar_cnt(int* __restrict__ cnt, int bm,
                                            int tid, int bar) {
  asm volatile("s_waitcnt vmcnt(0)" ::: "memory");  // h stores drained
  __syncthreads();
  if (tid == 0) {
    int* p = &cnt[(bar * 2 + bm) * 32];
    __hip_atomic_fetch_add(p, 1, __ATOMIC_RELAXED, __HIP_MEMORY_SCOPE_AGENT);
    while (__hip_atomic_load(p, __ATOMIC_RELAXED,
                             __HIP_MEMORY_SCOPE_AGENT) < 32) {}
  }
  __syncthreads();
}

// ---------------------------------------------------------------------------
__global__ void zero_ints(int* __restrict__ p, int n) {
  for (int i = blockIdx.x * 256 + threadIdx.x; i < n; i += gridDim.x * 256)
    p[i] = 0;
}

// ---------------------------------------------------------------------------
// Transpose + split: src fp32 [Krows][ld] (row offset k0) -> hi/lo bf16 [N][512]
// grid: (N/64, 512/64), block 256. (Wh only: recurrence needs full precision.)
__global__ void __launch_bounds__(256) transpose_split(
    const float* __restrict__ src, int ld, int k0,
    ushort_t* __restrict__ hi, ushort_t* __restrict__ lo) {
  __shared__ float tile[64][65];
  const int n0 = blockIdx.x * 64, kb = blockIdx.y * 64;
  #pragma unroll
  for (int i = 0; i < 16; ++i) {
    int idx = i * 256 + threadIdx.x;
    int kk = idx >> 6, nn = idx & 63;
    tile[kk][nn] = src[(size_t)(k0 + kb + kk) * ld + n0 + nn];
  }
  __syncthreads();
  #pragma unroll
  for (int i = 0; i < 16; ++i) {
    int idx = i * 256 + threadIdx.x;
    int nn = idx >> 6, kk = idx & 63;
    float x = tile[kk][nn];
    ushort_t h, l; splitbf(x, h, l);
    size_t o = (size_t)(n0 + nn) * 512 + kb + kk;
    hi[o] = h; lo[o] = l;
  }
}

// ---------------------------------------------------------------------------
// Transpose to fp16 (single plane): src fp32 rows k0..k0+511 of [*][ld]
// -> dst fp16 [N][512]. Used for Wx (z-error ~3e-5, see theory) and proj_W.
__global__ void __launch_bounds__(256) transpose_f16(
    const float* __restrict__ src, int ld, int k0, half_t* __restrict__ dst) {
  __shared__ float tile[64][65];
  const int n0 = blockIdx.x * 64, kb = blockIdx.y * 64;
  #pragma unroll
  for (int i = 0; i < 16; ++i) {
    int idx = i * 256 + threadIdx.x;
    int kk = idx >> 6, nn = idx & 63;
    tile[kk][nn] = src[(size_t)(k0 + kb + kk) * ld + n0 + nn];
  }
  __syncthreads();
  #pragma unroll
  for (int i = 0; i < 16; ++i) {
    int idx = i * 256 + threadIdx.x;
    int nn = idx >> 6, kk = idx & 63;
    dst[(size_t)(n0 + nn) * 512 + kb + kk] = (half_t)tile[kk][nn];
  }
}

// ---------------------------------------------------------------------------
// Embedding gather to fp16: row m = t*32+b of A gets E[ids[b*T+t]].
__global__ void __launch_bounds__(128) embed_f16(
    const int* __restrict__ ids, const float* __restrict__ E,
    half_t* __restrict__ A, int T) {
  const int m = blockIdx.x;
  const int b = m & 31, t = m >> 5;
  const int id = ids[b * T + t];
  float4 v = ((const float4*)(E + (size_t)id * 512))[threadIdx.x];
  half4 h = {(half_t)v.x, (half_t)v.y, (half_t)v.z, (half_t)v.w};
  ((half4*)(A + (size_t)m * 512))[threadIdx.x] = h;
}

// ---------------------------------------------------------------------------
// FP16 single-pass GEMM: C[M][N] = A[M][512] * B^T[N][512] (+bias).
// 128x128 tile, 4 waves, global_load_lds staging with pre-swizzled source
// (LDS dest linear). Grid (M/128, N/128) m-fast: blocks sharing a B-tile are
// dispatch-adjacent. Used for xz (bias) and vocab projection (no bias).
__global__ void __launch_bounds__(256, 2) gemm_f16(
    const half_t* __restrict__ A, const half_t* __restrict__ Bm,
    const float* __restrict__ bias, float* __restrict__ C, int N) {
  __shared__ __align__(16) half_t lA[128 * 64];
  __shared__ __align__(16) half_t lB[128 * 64];
  const int tid = threadIdx.x;
  const int lane = tid & 63, w = tid >> 6;
  const int wm = (w >> 1) * 64, wn = (w & 1) * 64;
  const int lm = lane & 15, lq = lane >> 4;
  const int m0 = blockIdx.x * 128, n0 = blockIdx.y * 128;

  f32x4 acc[4][4];
  #pragma unroll
  for (int i = 0; i < 4; ++i)
    #pragma unroll
    for (int j = 0; j < 4; ++j)
      acc[i][j] = (f32x4){0.f, 0.f, 0.f, 0.f};

  for (int kc = 0; kc < 8; ++kc) {
    if (kc) __syncthreads();
    #pragma unroll
    for (int i = 0; i < 4; ++i) {
      int cid = i * 256 + tid;
      int r = cid >> 3, cl = cid & 7;
      int csrc = cl ^ (r & 7);
      size_t goffA = (size_t)(m0 + r) * 512 + kc * 64 + csrc * 8;
      size_t goffB = (size_t)(n0 + r) * 512 + kc * 64 + csrc * 8;
      int ldso = (i * 256 + w * 64) * 8;
      gload16(A + goffA, lA + ldso);
      gload16(Bm + goffB, lB + ldso);
    }
    __syncthreads();
    #pragma unroll
    for (int ks = 0; ks < 2; ++ks) {
      half8 a[4], b[4];
      #pragma unroll
      for (int t = 0; t < 4; ++t) {
        int ra = wm + t * 16 + lm;
        int ca = (ks * 4 + lq) ^ (ra & 7);
        a[t] = *(const half8*)&lA[ra * 64 + ca * 8];
        int rb = wn + t * 16 + lm;
        int cb = (ks * 4 + lq) ^ (rb & 7);
        b[t] = *(const half8*)&lB[rb * 64 + cb * 8];
      }
      #pragma unroll
      for (int mt = 0; mt < 4; ++mt)
        #pragma unroll
        for (int nt = 0; nt < 4; ++nt)
          acc[mt][nt] = mfma16h(a[mt], b[nt], acc[mt][nt]);
    }
  }
  #pragma unroll
  for (int nt = 0; nt < 4; ++nt) {
    int col = n0 + wn + nt * 16 + lm;
    float bv = bias ? bias[col] : 0.f;
    #pragma unroll
    for (int mt = 0; mt < 4; ++mt) {
      int rbase = m0 + wm + mt * 16 + lq * 4;
      #pragma unroll
      for (int r = 0; r < 4; ++r)
        C[(size_t)(rbase + r) * N + col] = acc[mt][nt][r] + bv;
    }
  }
}

// ---------------------------------------------------------------------------
// Full enc+dec recurrence: 64 blocks x 256 thr, cooperative (co-residency),
// two independent 32-block barrier groups (bm=0 / bm=1 recurrences disjoint).
// Block = (bm in {0,1}: 16-batch tile) x (jg in [0,32): 16 H-cols). Wave = gate.
// Wh fragments live in registers (split-bf16: h errors compound 128 steps).
// h[s] lives in a PER-STEP buffer (129 total): writers use write-through
// relaxed-agent atomic stores, readers use plain loads on never-before-touched
// lines -> no acquire fence / L2 inv / wbl2 on the 128-step critical path.
// [R1-verified structure; barrier swapped for the counting barrier above.]
__global__ void __launch_bounds__(256, 1) lstm_recurrence(
    const ushort_t* __restrict__ eWh_hi, const ushort_t* __restrict__ eWh_lo,
    const ushort_t* __restrict__ dWh_hi, const ushort_t* __restrict__ dWh_lo,
    const float* __restrict__ xz_enc, const float* __restrict__ xz_dec,
    const int* __restrict__ len_enc, const int* __restrict__ len_dec,
    ushort_t* __restrict__ hseq_hi, ushort_t* __restrict__ hseq_lo,
    half_t* __restrict__ hs_f16, int* __restrict__ cnt) {
  const int tid = threadIdx.x;
  const int lane = tid & 63, g = tid >> 6;       // g = gate (i,j,f,o)
  const int lm = lane & 15, lq = lane >> 4;
  const int bm = blockIdx.x & 1, jg = blockIdx.x >> 1;

  __shared__ float z_x[4][16][17];
  __shared__ float c_st[16][17], h_st[16][17];

  const int bl = tid >> 4, nn = tid & 15;        // gate-phase mapping
  const int bglob = bm * 16 + bl;
  const int hcol = jg * 16 + nn;

  c_st[bl][nn] = 0.f; h_st[bl][nn] = 0.f;
  // h[0] = 0, write-through to LLC (step-0 buffer).
  __hip_atomic_store(&hseq_hi[bglob * 512 + hcol], (ushort_t)0,
                     __ATOMIC_RELAXED, __HIP_MEMORY_SCOPE_AGENT);
  __hip_atomic_store(&hseq_lo[bglob * 512 + hcol], (ushort_t)0,
                     __ATOMIC_RELAXED, __HIP_MEMORY_SCOPE_AGENT);
  const int lenE = len_enc[bglob], lenD = len_dec[bglob];

  // Preload encoder Wh fragments into registers.
  short8 fbh[16], fbl[16];
  const size_t browoff = (size_t)(g * 512 + jg * 16 + lm) * 512 + lq * 8;
  #pragma unroll
  for (int ks = 0; ks < 16; ++ks) {
    fbh[ks] = *(const short8*)(eWh_hi + browoff + ks * 32);
    fbl[ks] = *(const short8*)(eWh_lo + browoff + ks * 32);
  }

  // Prefetch step-0 gate inputs (independent of h -> issued before barrier).
  float pzi, pzj, pzf, pzo;
  {
    const size_t base = (size_t)bglob * 2048 + jg * 16 + nn;
    pzi = xz_enc[base];        pzj = xz_enc[base + 512];
    pzf = xz_enc[base + 1024]; pzo = xz_enc[base + 1536];
  }
  gridbar_cnt(cnt, bm, tid, 1);   // h[0] visible everywhere

  const size_t arow = (size_t)(bm * 16 + lm) * 512 + lq * 8;

  #pragma unroll 1
  for (int s = 0; s < 128; ++s) {
    if (s == 64) {  // switch to decoder weights (uniform branch)
      #pragma unroll
      for (int ks = 0; ks < 16; ++ks) {
        fbh[ks] = *(const short8*)(dWh_hi + browoff + ks * 32);
        fbl[ks] = *(const short8*)(dWh_lo + browoff + ks * 32);
      }
    }
    const ushort_t* hh = hseq_hi + (size_t)s * 16384;       // 32*512
    const ushort_t* hl = hseq_lo + (size_t)s * 16384;
    ushort_t* ohh = hseq_hi + (size_t)(s + 1) * 16384;
    ushort_t* ohl = hseq_lo + (size_t)(s + 1) * 16384;

    // 3 independent accumulator chains: dep depth 16 instead of 48.
    f32x4 a0 = (f32x4){0.f, 0.f, 0.f, 0.f};
    f32x4 a1 = (f32x4){0.f, 0.f, 0.f, 0.f};
    f32x4 a2 = (f32x4){0.f, 0.f, 0.f, 0.f};
    #pragma unroll
    for (int ks = 0; ks < 16; ++ks) {
      short8 ah = *(const short8*)(hh + arow + ks * 32);
      short8 al = *(const short8*)(hl + arow + ks * 32);
      a0 = mfma16(ah, fbh[ks], a0);
      a1 = mfma16(ah, fbl[ks], a1);
      a2 = mfma16(al, fbh[ks], a2);
    }
    #pragma unroll
    for (int r = 0; r < 4; ++r)
      z_x[g][lq * 4 + r][lm] = a0[r] + a1[r] + a2[r];
    __syncthreads();

    {  // gate phase: thread (bl, nn) owns one (b, H-col) cell
      const bool isdec = s >= 64;
      const int t = isdec ? s - 64 : s;
      const int len = isdec ? lenD : lenE;
      float zi = z_x[0][bl][nn] + pzi;
      float zj = z_x[1][bl][nn] + pzj;
      float zf = z_x[2][bl][nn] + pzf;
      float zo = z_x[3][bl][nn] + pzo;
      float co = c_st[bl][nn], ho = h_st[bl][nn];
      float cn = co * sigm(zf + 1.0f) + sigm(zi) * tanhf(zj);  // forget bias 1.0
      float hn = tanhf(cn) * sigm(zo);
      bool msk = t < len;
      float ck = msk ? cn : co;
      float hk = msk ? hn : ho;
      c_st[bl][nn] = ck; h_st[bl][nn] = hk;
      ushort_t hi, lo;
      splitbf(hk, hi, lo);
      // Write-through to LLC (per-step buffer s+1); no fence needed.
      __hip_atomic_store(&ohh[bglob * 512 + hcol], hi, __ATOMIC_RELAXED,
                         __HIP_MEMORY_SCOPE_AGENT);
      __hip_atomic_store(&ohl[bglob * 512 + hcol], lo, __ATOMIC_RELAXED,
                         __HIP_MEMORY_SCOPE_AGENT);
      if (isdec) {  // emitted output: zeroed past length; row = b*64 + t
        float hv = msk ? hn : 0.f;
        hs_f16[((size_t)bglob * 64 + t) * 512 + hcol] = (half_t)hv;
      }
    }
    if (s != 127) {
      // Prefetch next step's gate inputs (h-independent), then barrier (R1).
      const int sp = s + 1;
      const bool pd = sp >= 64;
      const float* xz = pd ? xz_dec : xz_enc;
      const int tp = pd ? sp - 64 : sp;
      const size_t base = ((size_t)tp * 32 + bglob) * 2048 + jg * 16 + nn;
      pzi = xz[base];        pzj = xz[base + 512];
      pzf = xz[base + 1024]; pzo = xz[base + 1536];
      gridbar_cnt(cnt, bm, tid, s + 2);
    }
  }
}

// ---------------------------------------------------------------------------
extern "C" void kernel_launch(void* const* d_in, const int* in_sizes, int n_in,
                              void* d_out, int out_size, void* d_ws, size_t ws_size,
                              hipStream_t stream) {
  (void)in_sizes; (void)n_in; (void)out_size; (void)ws_size;
  const int*   enc_ids = (const int*)d_in[0];
  const int*   dec_ids = (const int*)d_in[1];
  const int*   len_enc = (const int*)d_in[2];
  const int*   len_dec = (const int*)d_in[3];
  const float* E       = (const float*)d_in[4];
  const float* enc_W   = (const float*)d_in[5];
  const float* enc_b   = (const float*)d_in[6];
  const float* dec_W   = (const float*)d_in[7];
  const float* dec_b   = (const float*)d_in[8];
  const float* proj_W  = (const float*)d_in[9];

  char* w = (char*)d_ws;
  auto carve = [&](size_t bytes) -> char* {
    char* p = w; w += (bytes + 255) & ~(size_t)255; return p;
  };
  const size_t WSZ = 2048 * 512 * 2;  // [2048][512] 2B
  ushort_t* eWh_hi = (ushort_t*)carve(WSZ); ushort_t* eWh_lo = (ushort_t*)carve(WSZ);
  ushort_t* dWh_hi = (ushort_t*)carve(WSZ); ushort_t* dWh_lo = (ushort_t*)carve(WSZ);
  half_t*   eWxf   = (half_t*)carve(WSZ);
  half_t*   dWxf   = (half_t*)carve(WSZ);
  half_t*   pWf    = (half_t*)carve((size_t)32000 * 512 * 2);  // fp16 single
  half_t*   Aef    = (half_t*)carve(WSZ);
  half_t*   Adf    = (half_t*)carve(WSZ);
  float* xz_enc = (float*)carve((size_t)64 * 32 * 2048 * 4);
  float* xz_dec = (float*)carve((size_t)64 * 32 * 2048 * 4);
  half_t* hs_f16 = (half_t*)carve(WSZ);     // [2048][512] fp16 (row = b*64+t)
  // Per-step h buffers: 129 x [32][512] bf16 per plane (R1-proven layout).
  ushort_t* hseq_hi = (ushort_t*)carve((size_t)129 * 32 * 512 * 2);
  ushort_t* hseq_lo = (ushort_t*)carve((size_t)129 * 32 * 512 * 2);
  // Counting-barrier slots: (bar,bm) -> (bar*2+bm)*32 ints, bars 0..129.
  const int NCNT = 260 * 32;
  int* cnt = (int*)carve(NCNT * sizeof(int));

  dim3 blk(256);
  // Zero the barrier counters (graph-capture-safe plain kernel).
  zero_ints<<<33, 256, 0, stream>>>(cnt, NCNT);

  // Weight transposes: Wh split-bf16 (recurrence precision), Wx/proj fp16.
  transpose_split<<<dim3(32, 8),  blk, 0, stream>>>(enc_W, 2048, 512, eWh_hi, eWh_lo);
  transpose_split<<<dim3(32, 8),  blk, 0, stream>>>(dec_W, 2048, 512, dWh_hi, dWh_lo);
  transpose_f16<<<dim3(32, 8),    blk, 0, stream>>>(enc_W, 2048, 0, eWxf);
  transpose_f16<<<dim3(32, 8),    blk, 0, stream>>>(dec_W, 2048, 0, dWxf);
  transpose_f16<<<dim3(500, 8),   blk, 0, stream>>>(proj_W, 32000, 0, pWf);

  // Embedding gather (fp16, rows m = t*32+b)
  embed_f16<<<2048, 128, 0, stream>>>(enc_ids, E, Aef, 64);
  embed_f16<<<2048, 128, 0, stream>>>(dec_ids, E, Adf, 64);

  // Input-side gate pre-activations: xz[t][b][4H] = X @ W_x + b (fp16 1-pass;
  // z ~ 0.05 absolute -> fp16 error ~3e-5, negligible vs 1.64e-3 budget).
  gemm_f16<<<dim3(16, 16), blk, 0, stream>>>(Aef, eWxf, enc_b, xz_enc, 2048);
  gemm_f16<<<dim3(16, 16), blk, 0, stream>>>(Adf, dWxf, dec_b, xz_dec, 2048);

  // Recurrence (cooperative launch for co-residency; counting barrier inside)
  void* args[] = { &eWh_hi, &eWh_lo, &dWh_hi, &dWh_lo,
                   (void*)&xz_enc, (void*)&xz_dec,
                   (void*)&len_enc, (void*)&len_dec,
                   &hseq_hi, &hseq_lo, &hs_f16, &cnt };
  hipLaunchCooperativeKernel((void*)lstm_recurrence, dim3(64), dim3(256),
                             args, 0, stream);

  // Vocab projection (fp16 single-pass): out[b][t][v], rows match hs layout.
  const float* nobias = nullptr;
  gemm_f16<<<dim3(16, 250), blk, 0, stream>>>(hs_f16, pWf, nobias,
                                              (float*)d_out, 32000);
}

// Round 11
// 1405.317 us; speedup vs baseline: 1.0463x; 1.0463x over previous
//
#include <hip/hip_runtime.h>

// Problem constants: B=32, TX=TY=64, D=H=512, 4H=2048, V=32000.
typedef unsigned short ushort_t;
typedef _Float16 half_t;
typedef __attribute__((ext_vector_type(8))) short short8;     // 8 bf16 = 4 VGPRs
typedef __attribute__((ext_vector_type(8))) _Float16 half8;   // 8 fp16 = 4 VGPRs
typedef __attribute__((ext_vector_type(4))) _Float16 half4;
typedef __attribute__((ext_vector_type(4))) float f32x4;      // MFMA 16x16 acc

__device__ __forceinline__ ushort_t f2bf(float x) {
  union { float f; unsigned int u; } v; v.f = x;
  unsigned int r = v.u + 0x7fffu + ((v.u >> 16) & 1u);  // RNE
  return (ushort_t)(r >> 16);
}
__device__ __forceinline__ float bf2f(ushort_t h) {
  union { unsigned int u; float f; } v; v.u = ((unsigned int)h) << 16; return v.f;
}
__device__ __forceinline__ void splitbf(float x, ushort_t& hi, ushort_t& lo) {
  hi = f2bf(x);
  lo = f2bf(x - bf2f(hi));
}
__device__ __forceinline__ float sigm(float x) { return 1.f / (1.f + expf(-x)); }
__device__ __forceinline__ f32x4 mfma16(short8 a, short8 b, f32x4 c) {
  return __builtin_amdgcn_mfma_f32_16x16x32_bf16(a, b, c, 0, 0, 0);
}
__device__ __forceinline__ f32x4 mfma16h(half8 a, half8 b, f32x4 c) {
  return __builtin_amdgcn_mfma_f32_16x16x32_f16(a, b, c, 0, 0, 0);
}

// Async global->LDS, 16B per lane. LDS dest is wave-uniform base + lane*16
// (hardware rule, m104); global src is per-lane.
__device__ __forceinline__ void gload16(const void* g, void* l) {
  __builtin_amdgcn_global_load_lds(
      (const __attribute__((address_space(1))) unsigned int*)g,
      (__attribute__((address_space(3))) unsigned int*)l, 16, 0, 0);
}

// R1-verified broadcast-flag barrier over the 32-block bm-group (R10's
// counting barrier measured +49us WORSE: single-line fetch_add serializes 32
// RMWs at the MALL; 32 parallel flag lines broadcast+poll faster).
// flags[i*32] = monotone arrival counter of block i (128B slots). Poisoned ws
// reads negative -> no init needed. h data uses write-through relaxed-agent
// stores into per-step buffers + never-reused consumer lines, so no
// release/acquire cache maintenance is needed; vmcnt(0) drains the stores to
// the coherence point before the flag store.
#define BAR_NB 64
__device__ __forceinline__ void gridbar(int* __restrict__ flags, int bid,
                                        int bm, int tid, int bar) {
  asm volatile("s_waitcnt vmcnt(0)" ::: "memory");  // h stores drained
  __syncthreads();
  if (tid == 0)
    __hip_atomic_store(&flags[bid * 32], bar, __ATOMIC_RELAXED,
                       __HIP_MEMORY_SCOPE_AGENT);
  if (tid < 32) {  // poll only the 32 blocks of this bm-group (ids 2k+bm)
    while (__hip_atomic_load(&flags[(2 * tid + bm) * 32], __ATOMIC_RELAXED,
                             __HIP_MEMORY_SCOPE_AGENT) < bar) {}
  }
  __syncthreads();
}

// ---------------------------------------------------------------------------
// Fused weight transpose: 4 jobs via blockIdx.z.
//  job 0/1: enc/dec Wh rows 512..1023 -> split-bf16 (recurrence precision)
//  job 2/3: enc/dec Wx rows 0..511    -> fp16 single plane
// grid (32, 8, 4), block 256.
__global__ void __launch_bounds__(256) transpose_weights(
    const float* __restrict__ encW, const float* __restrict__ decW,
    ushort_t* __restrict__ eWh_hi, ushort_t* __restrict__ eWh_lo,
    ushort_t* __restrict__ dWh_hi, ushort_t* __restrict__ dWh_lo,
    half_t* __restrict__ eWxf, half_t* __restrict__ dWxf) {
  __shared__ float tile[64][65];
  const int job = blockIdx.z;
  const float* src = (job & 1) ? decW : encW;
  const int k0 = (job < 2) ? 512 : 0;
  const int n0 = blockIdx.x * 64, kb = blockIdx.y * 64;
  #pragma unroll
  for (int i = 0; i < 16; ++i) {
    int idx = i * 256 + threadIdx.x;
    int kk = idx >> 6, nn = idx & 63;
    tile[kk][nn] = src[(size_t)(k0 + kb + kk) * 2048 + n0 + nn];
  }
  __syncthreads();
  if (job < 2) {
    ushort_t* hi = (job & 1) ? dWh_hi : eWh_hi;
    ushort_t* lo = (job & 1) ? dWh_lo : eWh_lo;
    #pragma unroll
    for (int i = 0; i < 16; ++i) {
      int idx = i * 256 + threadIdx.x;
      int nn = idx >> 6, kk = idx & 63;
      ushort_t h, l; splitbf(tile[kk][nn], h, l);
      size_t o = (size_t)(n0 + nn) * 512 + kb + kk;
      hi[o] = h; lo[o] = l;
    }
  } else {
    half_t* dst = (job & 1) ? dWxf : eWxf;
    #pragma unroll
    for (int i = 0; i < 16; ++i) {
      int idx = i * 256 + threadIdx.x;
      int nn = idx >> 6, kk = idx & 63;
      dst[(size_t)(n0 + nn) * 512 + kb + kk] = (half_t)tile[kk][nn];
    }
  }
}

// ---------------------------------------------------------------------------
// Transpose to fp16 (single plane): proj_W fp32 [512][ld] -> fp16 [N][512].
__global__ void __launch_bounds__(256) transpose_f16(
    const float* __restrict__ src, int ld, half_t* __restrict__ dst) {
  __shared__ float tile[64][65];
  const int n0 = blockIdx.x * 64, kb = blockIdx.y * 64;
  #pragma unroll
  for (int i = 0; i < 16; ++i) {
    int idx = i * 256 + threadIdx.x;
    int kk = idx >> 6, nn = idx & 63;
    tile[kk][nn] = src[(size_t)(kb + kk) * ld + n0 + nn];
  }
  __syncthreads();
  #pragma unroll
  for (int i = 0; i < 16; ++i) {
    int idx = i * 256 + threadIdx.x;
    int nn = idx >> 6, kk = idx & 63;
    dst[(size_t)(n0 + nn) * 512 + kb + kk] = (half_t)tile[kk][nn];
  }
}

// ---------------------------------------------------------------------------
// Fused embedding gather (enc+dec) to fp16: grid 4096; blocks 0..2047 -> enc,
// 2048..4095 -> dec. Row m = t*32+b of A gets E[ids[b*64+t]].
__global__ void __launch_bounds__(128) embed_f16(
    const int* __restrict__ enc_ids, const int* __restrict__ dec_ids,
    const float* __restrict__ E,
    half_t* __restrict__ Ae, half_t* __restrict__ Ad) {
  const int which = blockIdx.x >> 11;
  const int m = blockIdx.x & 2047;
  const int* ids = which ? dec_ids : enc_ids;
  half_t* A = which ? Ad : Ae;
  const int b = m & 31, t = m >> 5;
  const int id = ids[b * 64 + t];
  float4 v = ((const float4*)(E + (size_t)id * 512))[threadIdx.x];
  half4 h = {(half_t)v.x, (half_t)v.y, (half_t)v.z, (half_t)v.w};
  ((half4*)(A + (size_t)m * 512))[threadIdx.x] = h;
}

// ---------------------------------------------------------------------------
// FP16 single-pass GEMM core: C[M][N] tile (m0,n0) = A * B^T (+bias).
// 128x128 tile, 4 waves, global_load_lds staging with pre-swizzled source
// (LDS dest linear). Verified in R9 (proj) and R10 (xz, absmax-neutral).
__device__ __forceinline__ void gemm_f16_core(
    const half_t* __restrict__ A, const half_t* __restrict__ Bm,
    const float* __restrict__ bias, float* __restrict__ C, int N,
    int m0, int n0, half_t* lA, half_t* lB) {
  const int tid = threadIdx.x;
  const int lane = tid & 63, w = tid >> 6;
  const int wm = (w >> 1) * 64, wn = (w & 1) * 64;
  const int lm = lane & 15, lq = lane >> 4;

  f32x4 acc[4][4];
  #pragma unroll
  for (int i = 0; i < 4; ++i)
    #pragma unroll
    for (int j = 0; j < 4; ++j)
      acc[i][j] = (f32x4){0.f, 0.f, 0.f, 0.f};

  for (int kc = 0; kc < 8; ++kc) {
    if (kc) __syncthreads();
    #pragma unroll
    for (int i = 0; i < 4; ++i) {
      int cid = i * 256 + tid;
      int r = cid >> 3, cl = cid & 7;
      int csrc = cl ^ (r & 7);
      size_t goffA = (size_t)(m0 + r) * 512 + kc * 64 + csrc * 8;
      size_t goffB = (size_t)(n0 + r) * 512 + kc * 64 + csrc * 8;
      int ldso = (i * 256 + w * 64) * 8;
      gload16(A + goffA, lA + ldso);
      gload16(Bm + goffB, lB + ldso);
    }
    __syncthreads();
    #pragma unroll
    for (int ks = 0; ks < 2; ++ks) {
      half8 a[4], b[4];
      #pragma unroll
      for (int t = 0; t < 4; ++t) {
        int ra = wm + t * 16 + lm;
        int ca = (ks * 4 + lq) ^ (ra & 7);
        a[t] = *(const half8*)&lA[ra * 64 + ca * 8];
        int rb = wn + t * 16 + lm;
        int cb = (ks * 4 + lq) ^ (rb & 7);
        b[t] = *(const half8*)&lB[rb * 64 + cb * 8];
      }
      #pragma unroll
      for (int mt = 0; mt < 4; ++mt)
        #pragma unroll
        for (int nt = 0; nt < 4; ++nt)
          acc[mt][nt] = mfma16h(a[mt], b[nt], acc[mt][nt]);
    }
  }
  #pragma unroll
  for (int nt = 0; nt < 4; ++nt) {
    int col = n0 + wn + nt * 16 + lm;
    float bv = bias ? bias[col] : 0.f;
    #pragma unroll
    for (int mt = 0; mt < 4; ++mt) {
      int rbase = m0 + wm + mt * 16 + lq * 4;
      #pragma unroll
      for (int r = 0; r < 4; ++r)
        C[(size_t)(rbase + r) * N + col] = acc[mt][nt][r] + bv;
    }
  }
}

// Vocab projection: grid (M/128, N/128) m-fast (B-tile sharers adjacent).
__global__ void __launch_bounds__(256, 2) gemm_f16(
    const half_t* __restrict__ A, const half_t* __restrict__ Bm,
    const float* __restrict__ bias, float* __restrict__ C, int N) {
  __shared__ __align__(16) half_t lA[128 * 64];
  __shared__ __align__(16) half_t lB[128 * 64];
  gemm_f16_core(A, Bm, bias, C, N, blockIdx.x * 128, blockIdx.y * 128, lA, lB);
}

// Fused xz GEMMs: grid (32, 16); blocks x<16 -> encoder, x>=16 -> decoder.
__global__ void __launch_bounds__(256, 2) gemm_f16_xz(
    const half_t* __restrict__ Ae, const half_t* __restrict__ Ad,
    const half_t* __restrict__ eW, const half_t* __restrict__ dW,
    const float* __restrict__ eb, const float* __restrict__ db,
    float* __restrict__ xe, float* __restrict__ xd) {
  __shared__ __align__(16) half_t lA[128 * 64];
  __shared__ __align__(16) half_t lB[128 * 64];
  const bool dec = blockIdx.x >= 16;
  gemm_f16_core(dec ? Ad : Ae, dec ? dW : eW, dec ? db : eb, dec ? xd : xe,
                2048, (blockIdx.x & 15) * 128, blockIdx.y * 128, lA, lB);
}

// ---------------------------------------------------------------------------
// Full enc+dec recurrence: 64 blocks x 256 thr, cooperative (co-residency),
// two independent 32-block barrier groups (bm=0 / bm=1 recurrences disjoint).
// Block = (bm in {0,1}: 16-batch tile) x (jg in [0,32): 16 H-cols). Wave = gate.
// Wh fragments live in registers (split-bf16: h errors compound 128 steps).
// h[s] lives in a PER-STEP buffer (129 total): writers use write-through
// relaxed-agent atomic stores, readers use plain loads on never-before-touched
// lines -> no acquire fence / L2 inv / wbl2 on the 128-step critical path.
// [R1-EXACT verified structure + broadcast-flag barrier (903us); R10's
// counting barrier reverted (+49us regression).]
__global__ void __launch_bounds__(256, 1) lstm_recurrence(
    const ushort_t* __restrict__ eWh_hi, const ushort_t* __restrict__ eWh_lo,
    const ushort_t* __restrict__ dWh_hi, const ushort_t* __restrict__ dWh_lo,
    const float* __restrict__ xz_enc, const float* __restrict__ xz_dec,
    const int* __restrict__ len_enc, const int* __restrict__ len_dec,
    ushort_t* __restrict__ hseq_hi, ushort_t* __restrict__ hseq_lo,
    half_t* __restrict__ hs_f16, int* __restrict__ flags) {
  const int tid = threadIdx.x;
  const int lane = tid & 63, g = tid >> 6;       // g = gate (i,j,f,o)
  const int lm = lane & 15, lq = lane >> 4;
  const int bm = blockIdx.x & 1, jg = blockIdx.x >> 1;

  __shared__ float z_x[4][16][17];
  __shared__ float c_st[16][17], h_st[16][17];

  const int bl = tid >> 4, nn = tid & 15;        // gate-phase mapping
  const int bglob = bm * 16 + bl;
  const int hcol = jg * 16 + nn;

  c_st[bl][nn] = 0.f; h_st[bl][nn] = 0.f;
  // h[0] = 0, write-through to LLC (step-0 buffer).
  __hip_atomic_store(&hseq_hi[bglob * 512 + hcol], (ushort_t)0,
                     __ATOMIC_RELAXED, __HIP_MEMORY_SCOPE_AGENT);
  __hip_atomic_store(&hseq_lo[bglob * 512 + hcol], (ushort_t)0,
                     __ATOMIC_RELAXED, __HIP_MEMORY_SCOPE_AGENT);
  const int lenE = len_enc[bglob], lenD = len_dec[bglob];

  // Preload encoder Wh fragments into registers.
  short8 fbh[16], fbl[16];
  const size_t browoff = (size_t)(g * 512 + jg * 16 + lm) * 512 + lq * 8;
  #pragma unroll
  for (int ks = 0; ks < 16; ++ks) {
    fbh[ks] = *(const short8*)(eWh_hi + browoff + ks * 32);
    fbl[ks] = *(const short8*)(eWh_lo + browoff + ks * 32);
  }

  // Prefetch step-0 gate inputs (independent of h -> issued before barrier).
  float pzi, pzj, pzf, pzo;
  {
    const size_t base = (size_t)bglob * 2048 + jg * 16 + nn;
    pzi = xz_enc[base];        pzj = xz_enc[base + 512];
    pzf = xz_enc[base + 1024]; pzo = xz_enc[base + 1536];
  }
  gridbar(flags, blockIdx.x, bm, tid, 1);   // h[0] visible everywhere

  const size_t arow = (size_t)(bm * 16 + lm) * 512 + lq * 8;

  #pragma unroll 1
  for (int s = 0; s < 128; ++s) {
    if (s == 64) {  // switch to decoder weights (uniform branch)
      #pragma unroll
      for (int ks = 0; ks < 16; ++ks) {
        fbh[ks] = *(const short8*)(dWh_hi + browoff + ks * 32);
        fbl[ks] = *(const short8*)(dWh_lo + browoff + ks * 32);
      }
    }
    const ushort_t* hh = hseq_hi + (size_t)s * 16384;       // 32*512
    const ushort_t* hl = hseq_lo + (size_t)s * 16384;
    ushort_t* ohh = hseq_hi + (size_t)(s + 1) * 16384;
    ushort_t* ohl = hseq_lo + (size_t)(s + 1) * 16384;

    // 3 independent accumulator chains: dep depth 16 instead of 48.
    f32x4 a0 = (f32x4){0.f, 0.f, 0.f, 0.f};
    f32x4 a1 = (f32x4){0.f, 0.f, 0.f, 0.f};
    f32x4 a2 = (f32x4){0.f, 0.f, 0.f, 0.f};
    #pragma unroll
    for (int ks = 0; ks < 16; ++ks) {
      short8 ah = *(const short8*)(hh + arow + ks * 32);
      short8 al = *(const short8*)(hl + arow + ks * 32);
      a0 = mfma16(ah, fbh[ks], a0);
      a1 = mfma16(ah, fbl[ks], a1);
      a2 = mfma16(al, fbh[ks], a2);
    }
    #pragma unroll
    for (int r = 0; r < 4; ++r)
      z_x[g][lq * 4 + r][lm] = a0[r] + a1[r] + a2[r];
    __syncthreads();

    {  // gate phase: thread (bl, nn) owns one (b, H-col) cell
      const bool isdec = s >= 64;
      const int t = isdec ? s - 64 : s;
      const int len = isdec ? lenD : lenE;
      float zi = z_x[0][bl][nn] + pzi;
      float zj = z_x[1][bl][nn] + pzj;
      float zf = z_x[2][bl][nn] + pzf;
      float zo = z_x[3][bl][nn] + pzo;
      float co = c_st[bl][nn], ho = h_st[bl][nn];
      float cn = co * sigm(zf + 1.0f) + sigm(zi) * tanhf(zj);  // forget bias 1.0
      float hn = tanhf(cn) * sigm(zo);
      bool msk = t < len;
      float ck = msk ? cn : co;
      float hk = msk ? hn : ho;
      c_st[bl][nn] = ck; h_st[bl][nn] = hk;
      ushort_t hi, lo;
      splitbf(hk, hi, lo);
      // Write-through to LLC (per-step buffer s+1); no fence needed.
      __hip_atomic_store(&ohh[bglob * 512 + hcol], hi, __ATOMIC_RELAXED,
                         __HIP_MEMORY_SCOPE_AGENT);
      __hip_atomic_store(&ohl[bglob * 512 + hcol], lo, __ATOMIC_RELAXED,
                         __HIP_MEMORY_SCOPE_AGENT);
      if (isdec) {  // emitted output: zeroed past length; row = b*64 + t
        float hv = msk ? hn : 0.f;
        hs_f16[((size_t)bglob * 64 + t) * 512 + hcol] = (half_t)hv;
      }
    }
    if (s != 127) {
      // Prefetch next step's gate inputs (h-independent), then barrier (R1).
      const int sp = s + 1;
      const bool pd = sp >= 64;
      const float* xz = pd ? xz_dec : xz_enc;
      const int tp = pd ? sp - 64 : sp;
      const size_t base = ((size_t)tp * 32 + bglob) * 2048 + jg * 16 + nn;
      pzi = xz[base];        pzj = xz[base + 512];
      pzf = xz[base + 1024]; pzo = xz[base + 1536];
      gridbar(flags, blockIdx.x, bm, tid, s + 2);
    }
  }
}

// ---------------------------------------------------------------------------
extern "C" void kernel_launch(void* const* d_in, const int* in_sizes, int n_in,
                              void* d_out, int out_size, void* d_ws, size_t ws_size,
                              hipStream_t stream) {
  (void)in_sizes; (void)n_in; (void)out_size; (void)ws_size;
  const int*   enc_ids = (const int*)d_in[0];
  const int*   dec_ids = (const int*)d_in[1];
  const int*   len_enc = (const int*)d_in[2];
  const int*   len_dec = (const int*)d_in[3];
  const float* E       = (const float*)d_in[4];
  const float* enc_W   = (const float*)d_in[5];
  const float* enc_b   = (const float*)d_in[6];
  const float* dec_W   = (const float*)d_in[7];
  const float* dec_b   = (const float*)d_in[8];
  const float* proj_W  = (const float*)d_in[9];

  char* w = (char*)d_ws;
  auto carve = [&](size_t bytes) -> char* {
    char* p = w; w += (bytes + 255) & ~(size_t)255; return p;
  };
  const size_t WSZ = 2048 * 512 * 2;  // [2048][512] 2B
  ushort_t* eWh_hi = (ushort_t*)carve(WSZ); ushort_t* eWh_lo = (ushort_t*)carve(WSZ);
  ushort_t* dWh_hi = (ushort_t*)carve(WSZ); ushort_t* dWh_lo = (ushort_t*)carve(WSZ);
  half_t*   eWxf   = (half_t*)carve(WSZ);
  half_t*   dWxf   = (half_t*)carve(WSZ);
  half_t*   pWf    = (half_t*)carve((size_t)32000 * 512 * 2);  // fp16 single
  half_t*   Aef    = (half_t*)carve(WSZ);
  half_t*   Adf    = (half_t*)carve(WSZ);
  float* xz_enc = (float*)carve((size_t)64 * 32 * 2048 * 4);
  float* xz_dec = (float*)carve((size_t)64 * 32 * 2048 * 4);
  half_t* hs_f16 = (half_t*)carve(WSZ);     // [2048][512] fp16 (row = b*64+t)
  // Per-step h buffers: 129 x [32][512] bf16 per plane (R1-proven layout).
  ushort_t* hseq_hi = (ushort_t*)carve((size_t)129 * 32 * 512 * 2);
  ushort_t* hseq_lo = (ushort_t*)carve((size_t)129 * 32 * 512 * 2);
  int* flags = (int*)carve(BAR_NB * 32 * sizeof(int));

  dim3 blk(256);
  // Fused weight transposes: Wh split-bf16 + Wx fp16 in ONE launch.
  transpose_weights<<<dim3(32, 8, 4), blk, 0, stream>>>(
      enc_W, dec_W, eWh_hi, eWh_lo, dWh_hi, dWh_lo, eWxf, dWxf);
  // Projection weight fp16 transpose.
  transpose_f16<<<dim3(500, 8), blk, 0, stream>>>(proj_W, 32000, pWf);

  // Fused embedding gather (enc+dec, fp16, rows m = t*32+b).
  embed_f16<<<4096, 128, 0, stream>>>(enc_ids, dec_ids, E, Aef, Adf);

  // Fused input-side gate pre-activations (enc+dec): xz = X @ W_x + b.
  gemm_f16_xz<<<dim3(32, 16), blk, 0, stream>>>(Aef, Adf, eWxf, dWxf,
                                                enc_b, dec_b, xz_enc, xz_dec);

  // Recurrence (cooperative launch for co-residency; R1 flag barrier inside)
  void* args[] = { &eWh_hi, &eWh_lo, &dWh_hi, &dWh_lo,
                   (void*)&xz_enc, (void*)&xz_dec,
                   (void*)&len_enc, (void*)&len_dec,
                   &hseq_hi, &hseq_lo, &hs_f16, &flags };
  hipLaunchCooperativeKernel((void*)lstm_recurrence, dim3(64), dim3(256),
                             args, 0, stream);

  // Vocab projection (fp16 single-pass): out[b][t][v], rows match hs layout.
  const float* nobias = nullptr;
  gemm_f16<<<dim3(16, 250), blk, 0, stream>>>(hs_f16, pWf, nobias,
                                              (float*)d_out, 32000);
}